// Round 16
// baseline (267.126 us; speedup 1.0000x reference)
//
#include <hip/hip_runtime.h>
#include <math.h>

#define BB 16
#define SS 512
#define HH 768
#define WW 256
#define VV 32000
#define NROWS (BB*WW)          // 4096
#define NCHUNK 500             // 64-wide v chunks
#define BM 128
#define BN 128
#define BK 64                  // fp8: 64 bytes per row per k-tile
#define NKT (HH/BK)            // 12
#define NMT (NROWS/BM)         // 32
#define NVT (VV/BN)            // 250
#define NWG (NMT*NVT)          // 8000
#define NPX (NWG/8)            // 1000 tiles per XCD chunk
#define NBLK 1024              // persistent blocks = 4/CU
#define WSCALE 64.0f
#define WISCALE (1.0f/64.0f)

typedef __attribute__((ext_vector_type(4))) float f32x4;

#define GLOAD16(g, l) __builtin_amdgcn_global_load_lds( \
    (const __attribute__((address_space(1))) void*)(g), \
    (__attribute__((address_space(3))) void*)(l), 16, 0, 0)

// pack 4 floats -> 4 fp8 e4m3 bytes (OCP)
__device__ __forceinline__ unsigned int pk4_fp8(float a0, float a1, float a2, float a3) {
    int r = __builtin_amdgcn_cvt_pk_fp8_f32(a0, a1, 0, false);
    r = __builtin_amdgcn_cvt_pk_fp8_f32(a2, a3, r, true);
    return (unsigned int)r;
}

// ---------------- fused prep: pooling (blocks 0..4095) + W transpose (rest) ----------------
// Both outputs use the half-swap-by-row-bit3 fp8 storage feeding the
// conflict-free LDS read swizzle in logits_kernel.
__global__ __launch_bounds__(256) void prep_kernel(
    const float* __restrict__ h, const int* __restrict__ wid,
    unsigned int* __restrict__ pooled32,
    const float* __restrict__ Wc, unsigned char* __restrict__ Wt)
{
    __shared__ int s_wid[SS];
    __shared__ float S[64][65];
    const int tid = threadIdx.x;

    if (blockIdx.x < NROWS) {
        // ---- pooling: one block per (b, w), binary search over sorted wid ----
        int blk = blockIdx.x;
        int b = blk >> 8;
        int w = blk & 255;
        for (int i = tid; i < SS; i += 256) s_wid[i] = wid[b*SS + i];
        __syncthreads();
        int lo = 0, hi = SS;
        while (lo < hi) { int mid = (lo + hi) >> 1; if (s_wid[mid] < w) lo = mid + 1; else hi = mid; }
        int start = lo;
        hi = SS;
        while (lo < hi) { int mid = (lo + hi) >> 1; if (s_wid[mid] <= w) lo = mid + 1; else hi = mid; }
        int end = lo;
        int cnt = end - start;

        if (tid < 192) {
            float4 a = {0.f, 0.f, 0.f, 0.f};
            const float* hb = h + (size_t)b*SS*HH;
            for (int s = start; s < end; ++s) {
                float4 r = *(const float4*)&hb[(size_t)s*HH + tid*4];
                a.x += r.x; a.y += r.y; a.z += r.z; a.w += r.w;
            }
            float inv = (cnt > 0) ? (1.0f / (float)cnt) : 0.0f;
            int p = (blk >> 3) & 1;                 // row bit3 -> swap 8B halves
            pooled32[blk*192 + (tid ^ (p << 1))] = pk4_fp8(a.x*inv, a.y*inv, a.z*inv, a.w*inv);
        }
    } else {
        // ---- W convert+transpose: (768,32000) f32 -> (32000,768) fp8 x64 ----
        int idx = blockIdx.x - NROWS;              // 0..5999
        const int v0 = (idx % (VV/64)) * 64;
        const int k0 = (idx / (VV/64)) * 64;
        #pragma unroll
        for (int j = 0; j < 4; ++j) {
            int ix = tid + j*256;
            int kr = ix >> 4;
            int vs = ix & 15;
            float4 f = *(const float4*)&Wc[(size_t)(k0+kr)*VV + v0 + vs*4];
            S[kr][vs*4+0] = f.x; S[kr][vs*4+1] = f.y;
            S[kr][vs*4+2] = f.z; S[kr][vs*4+3] = f.w;
        }
        __syncthreads();
        #pragma unroll
        for (int j = 0; j < 2; ++j) {
            int ix = tid + j*256;
            int vi = ix >> 3;     // 0..63 (row within tile)
            int ks = ix & 7;      // 0..7 (8B seg)
            float f[8];
            #pragma unroll
            for (int i = 0; i < 8; ++i) f[i] = S[ks*8+i][vi] * WSCALE;
            uint2 o;
            o.x = pk4_fp8(f[0], f[1], f[2], f[3]);
            o.y = pk4_fp8(f[4], f[5], f[6], f[7]);
            int p = (vi >> 3) & 1;                  // row bit3 -> swap 8B halves
            *(uint2*)&Wt[(size_t)(v0+vi)*HH + k0 + (ks ^ p)*8] = o;
        }
    }
}

// ---------------- fp8 MFMA GEMM: persistent blocks + cross-tile prefetch ----------------
// R15 geometry (proven best: 0 conflicts, no spill, 4 blocks/CU, T5) made
// persistent: 1024 blocks, each loops ~8 tiles of its XCD chunk.
// Per tile: kt=1..10 stage (this,kt+1); kt=11 stages (NEXT tile, kt0) into
// buf0 (readers passed kt=10 barrier -> WAR safe); epilogue stages
// (NEXT, kt1) into buf1 (safe after kt=11 barrier). kt=0 stages nothing.
// Prologue stall paid once per block; epilogue VALU overlaps next staging.
__global__ __launch_bounds__(256, 4) void logits_kernel(
    const unsigned char* __restrict__ Pb, const unsigned char* __restrict__ Wt,
    const float* __restrict__ bc, const int* __restrict__ targets,
    float* __restrict__ pmax, float* __restrict__ psum,
    float* __restrict__ tlogit)
{
    __shared__ unsigned char Alds[2][BM*BK];   // 2 x 8 KB
    __shared__ unsigned char Blds[2][BN*BK];   // 2 x 8 KB

    const int bid = blockIdx.x;     // 0..1023
    const int xcd = bid & 7;
    const int lid = bid >> 3;       // 0..127: position within XCD chunk

    const int t = threadIdx.x;
    const int w = t >> 6;           // wave 0..3
    const int lane = t & 63;
    const int r16 = lane & 15;
    const int kb = lane >> 4;       // 0..3 (8-byte k-seg within 32)
    const int wr = w >> 1;          // 0..1 (M)
    const int wc = w & 1;           // 0..1 (N)

    // staging: one call = 64 lanes x 16 B = 16 rows x 64 B; lane = rr*4 + s
    const int rr = lane >> 2;                     // 0..15 row within call
    const int sg = (lane & 3) ^ ((rr >> 1) & 3);  // pre-swizzled global 16B slot

    #define STAGEP(BUF, R0, V0, KT) do {                                          \
        const int k0_ = (KT) * BK;                                                \
        _Pragma("unroll")                                                         \
        for (int j_ = 0; j_ < 2; ++j_) {                                          \
            int ca_ = w*2 + j_;                                                   \
            GLOAD16(Pb + (size_t)((R0) + ca_*16 + rr)*HH + k0_ + sg*16,           \
                    &Alds[BUF][ca_*1024]);                                        \
            GLOAD16(Wt + (size_t)((V0) + ca_*16 + rr)*HH + k0_ + sg*16,           \
                    &Blds[BUF][ca_*1024]);                                        \
        }                                                                         \
    } while (0)

    const int swz2 = (r16 >> 1) & 3;
    const int swz3 = (r16 >> 3) & 1;

    // prologue: stage first tile's kt0+kt1 (only cold stall in the block)
    {
        const int wg0 = xcd*NPX + lid;
        const int r0 = (wg0 & (NMT-1)) * BM;
        const int c0 = (wg0 >> 5) * BN;
        STAGEP(0, r0, c0, 0);
        STAGEP(1, r0, c0, 1);
        __syncthreads();
    }

    for (int wci = lid; wci < NPX; wci += (NBLK/8)) {
        const int wg = xcd*NPX + wci;
        const int mt = wg & (NMT-1);
        const int vt = wg >> 5;
        const int row0 = mt * BM;
        const int v0 = vt * BN;

        const int wciN = wci + (NBLK/8);
        const bool hasNext = (wciN < NPX);
        const int wgN = xcd*NPX + (hasNext ? wciN : 0);
        const int row0N = (wgN & (NMT-1)) * BM;
        const int v0N = (wgN >> 5) * BN;

        f32x4 acc[4][4];
        #pragma unroll
        for (int mf = 0; mf < 4; ++mf)
            #pragma unroll
            for (int nf = 0; nf < 4; ++nf)
                acc[mf][nf] = (f32x4){0.f, 0.f, 0.f, 0.f};

        #pragma unroll
        for (int kt = 0; kt < NKT; ++kt) {
            const int buf = kt & 1;

            // stage: kt=0 nothing (pre-staged); kt=1..10 -> (this, kt+1);
            // kt=11 -> (next, kt0) into buf0
            if (kt >= 1 && kt + 1 < NKT) {
                STAGEP(buf ^ 1, row0, v0, kt + 1);
            } else if (kt == NKT - 1) {
                if (hasNext) STAGEP(0, row0N, v0N, 0);
            }

            long af[4][2], bfv[4][2];
            #pragma unroll
            for (int ks = 0; ks < 2; ++ks) {
                const int idx8 = ks*4 + kb;                       // 0..7
                const int off = (((idx8 >> 1) ^ swz2) << 4) | (((idx8 & 1) ^ swz3) << 3);
                #pragma unroll
                for (int mf = 0; mf < 4; ++mf)
                    af[mf][ks] = *(const long*)&Alds[buf][(wr*64 + mf*16 + r16)*BK + off];
                #pragma unroll
                for (int nf = 0; nf < 4; ++nf)
                    bfv[nf][ks] = *(const long*)&Blds[buf][(wc*64 + nf*16 + r16)*BK + off];
            }

            __builtin_amdgcn_s_setprio(1);
            #pragma unroll
            for (int ks = 0; ks < 2; ++ks)
                #pragma unroll
                for (int mf = 0; mf < 4; ++mf)
                    #pragma unroll
                    for (int nf = 0; nf < 4; ++nf)
                        acc[mf][nf] = __builtin_amdgcn_mfma_f32_16x16x32_fp8_fp8(
                            af[mf][ks], bfv[nf][ks], acc[mf][nf], 0, 0, 0);
            __builtin_amdgcn_s_setprio(0);

            __syncthreads();
        }

        // stage next tile's kt1 into buf1 (free after kt=11 barrier);
        // its latency hides under the epilogue below
        if (hasNext) STAGEP(1, row0N, v0N, 1);

        // epilogue: unscale + bias + per-row max/sumexp over wave's 64 cols
        const int cchunk = vt*2 + wc;
        float bias[4];
        #pragma unroll
        for (int nf = 0; nf < 4; ++nf) bias[nf] = bc[v0 + wc*64 + nf*16 + r16];

        #pragma unroll
        for (int mf = 0; mf < 4; ++mf) {
            #pragma unroll
            for (int j = 0; j < 4; ++j) {
                const int row = row0 + wr*64 + mf*16 + kb*4 + j;
                float v[4]; float mx = -INFINITY;
                #pragma unroll
                for (int nf = 0; nf < 4; ++nf) {
                    v[nf] = acc[mf][nf][j]*WISCALE + bias[nf];
                    mx = fmaxf(mx, v[nf]);
                }
                #pragma unroll
                for (int off = 1; off < 16; off <<= 1)
                    mx = fmaxf(mx, __shfl_xor(mx, off, 16));
                float se = 0.f;
                #pragma unroll
                for (int nf = 0; nf < 4; ++nf) se += __expf(v[nf] - mx);
                #pragma unroll
                for (int off = 1; off < 16; off <<= 1)
                    se += __shfl_xor(se, off, 16);
                if (r16 == 0) {
                    pmax[(size_t)row*NCHUNK + cchunk] = mx;
                    psum[(size_t)row*NCHUNK + cchunk] = se;
                }
                int tg = targets[row];
                int base = v0 + wc*64 + r16;
                #pragma unroll
                for (int nf = 0; nf < 4; ++nf)
                    if (tg == base + nf*16) tlogit[row] = v[nf];
            }
        }
    }
}

// ---------------- combine chunk partials -> per-row loss ----------------
__global__ __launch_bounds__(256) void reduce_kernel(
    const float* __restrict__ pmax, const float* __restrict__ psum,
    const float* __restrict__ tlogit, const int* __restrict__ targets,
    float* __restrict__ rowloss)
{
    const int row = blockIdx.x;
    const int tid = threadIdx.x;
    float m0 = (tid       < NCHUNK) ? pmax[(size_t)row*NCHUNK + tid]       : -INFINITY;
    float m1 = (tid + 256 < NCHUNK) ? pmax[(size_t)row*NCHUNK + tid + 256] : -INFINITY;
    float mw = fmaxf(m0, m1);
    #pragma unroll
    for (int off = 1; off < 64; off <<= 1)
        mw = fmaxf(mw, __shfl_xor(mw, off));
    __shared__ float smax[4];
    __shared__ float ssum[4];
    const int wave = tid >> 6;
    if ((tid & 63) == 0) smax[wave] = mw;
    __syncthreads();
    float mx = fmaxf(fmaxf(smax[0], smax[1]), fmaxf(smax[2], smax[3]));
    float s = 0.f;
    if (tid       < NCHUNK) s += psum[(size_t)row*NCHUNK + tid]       * __expf(m0 - mx);
    if (tid + 256 < NCHUNK) s += psum[(size_t)row*NCHUNK + tid + 256] * __expf(m1 - mx);
    #pragma unroll
    for (int off = 1; off < 64; off <<= 1)
        s += __shfl_xor(s, off);
    if ((tid & 63) == 0) ssum[wave] = s;
    __syncthreads();
    if (tid == 0) {
        float st = ssum[0] + ssum[1] + ssum[2] + ssum[3];
        float lse = mx + logf(st);
        int tg = targets[row];
        rowloss[row] = (tg != 0) ? (lse - tlogit[row]) : 0.0f;
    }
}

// ---------------- final sum over rows ----------------
__global__ __launch_bounds__(256) void finalize_kernel(
    const float* __restrict__ rowloss, const int* __restrict__ targets,
    float* __restrict__ out)
{
    const int tid = threadIdx.x;
    float s = 0.f; float c = 0.f;
    for (int i = tid; i < NROWS; i += 256) {
        s += rowloss[i];
        c += (targets[i] != 0) ? 1.0f : 0.0f;
    }
    #pragma unroll
    for (int off = 1; off < 64; off <<= 1) {
        s += __shfl_xor(s, off);
        c += __shfl_xor(c, off);
    }
    __shared__ float ss[4], sc[4];
    const int wave = tid >> 6;
    if ((tid & 63) == 0) { ss[wave] = s; sc[wave] = c; }
    __syncthreads();
    if (tid == 0) {
        float st = ss[0]+ss[1]+ss[2]+ss[3];
        float ct = sc[0]+sc[1]+sc[2]+sc[3];
        out[0] = st / fmaxf(ct, 1.0f);
    }
}

extern "C" void kernel_launch(void* const* d_in, const int* in_sizes, int n_in,
                              void* d_out, int out_size, void* d_ws, size_t ws_size,
                              hipStream_t stream) {
    const float* h       = (const float*)d_in[0];   // (16,512,768) f32
    const int*   wid     = (const int*)  d_in[1];   // (16,512) i32
    const int*   targets = (const int*)  d_in[2];   // (16,256) i32
    const float* Wc      = (const float*)d_in[3];   // (768,32000) f32
    const float* bc      = (const float*)d_in[4];   // (32000,) f32
    float* out = (float*)d_out;

    unsigned char* pooled = (unsigned char*)d_ws;                // 4096*768 fp8
    unsigned char* Wt     = pooled + (size_t)NROWS*HH;           // 32000*768 fp8
    float* pmax  = (float*)(Wt + (size_t)HH*VV);                 // 4096*500
    float* psum  = pmax + (size_t)NROWS*NCHUNK;                  // 4096*500
    float* tlog  = psum + (size_t)NROWS*NCHUNK;                  // 4096
    float* rowl  = tlog + NROWS;                                 // 4096

    prep_kernel<<<NROWS + (VV/64)*(HH/64), 256, 0, stream>>>(
        h, wid, (unsigned int*)pooled, Wc, Wt);
    logits_kernel<<<NBLK, 256, 0, stream>>>(
        pooled, Wt, bc, targets, pmax, psum, tlog);
    reduce_kernel<<<NROWS, 256, 0, stream>>>(pmax, psum, tlog, targets, rowl);
    finalize_kernel<<<1, 256, 0, stream>>>(rowl, targets, out);
}

// Round 17
// 257.009 us; speedup vs baseline: 1.0394x; 1.0394x over previous
//
#include <hip/hip_runtime.h>
#include <math.h>

#define BB 16
#define SS 512
#define HH 768
#define WW 256
#define VV 32000
#define NROWS (BB*WW)          // 4096
#define NCHUNK 500             // 64-wide v chunks
#define BM 128
#define BN 128
#define BK 64                  // fp8: 64 bytes per row per k-tile
#define NKT (HH/BK)            // 12
#define NMT (NROWS/BM)         // 32
#define NVT (VV/BN)            // 250
#define NWG (NMT*NVT)          // 8000
#define NPX (NWG/8)            // 1000 tiles per XCD chunk
#define NBLK 1024              // persistent blocks = 4/CU
#define TRUN 8                 // consecutive tiles per block (125*8 = 1000)
#define WSCALE 64.0f
#define WISCALE (1.0f/64.0f)

typedef __attribute__((ext_vector_type(4))) float f32x4;

#define GLOAD16(g, l) __builtin_amdgcn_global_load_lds( \
    (const __attribute__((address_space(1))) void*)(g), \
    (__attribute__((address_space(3))) void*)(l), 16, 0, 0)

// pack 4 floats -> 4 fp8 e4m3 bytes (OCP)
__device__ __forceinline__ unsigned int pk4_fp8(float a0, float a1, float a2, float a3) {
    int r = __builtin_amdgcn_cvt_pk_fp8_f32(a0, a1, 0, false);
    r = __builtin_amdgcn_cvt_pk_fp8_f32(a2, a3, r, true);
    return (unsigned int)r;
}

// ---------------- fused prep: pooling (blocks 0..4095) + W transpose (rest) ----------------
// Both outputs use the half-swap-by-row-bit3 fp8 storage feeding the
// conflict-free LDS read swizzle in logits_kernel.
__global__ __launch_bounds__(256) void prep_kernel(
    const float* __restrict__ h, const int* __restrict__ wid,
    unsigned int* __restrict__ pooled32,
    const float* __restrict__ Wc, unsigned char* __restrict__ Wt)
{
    __shared__ int s_wid[SS];
    __shared__ float S[64][65];
    const int tid = threadIdx.x;

    if (blockIdx.x < NROWS) {
        // ---- pooling: one block per (b, w), binary search over sorted wid ----
        int blk = blockIdx.x;
        int b = blk >> 8;
        int w = blk & 255;
        for (int i = tid; i < SS; i += 256) s_wid[i] = wid[b*SS + i];
        __syncthreads();
        int lo = 0, hi = SS;
        while (lo < hi) { int mid = (lo + hi) >> 1; if (s_wid[mid] < w) lo = mid + 1; else hi = mid; }
        int start = lo;
        hi = SS;
        while (lo < hi) { int mid = (lo + hi) >> 1; if (s_wid[mid] <= w) lo = mid + 1; else hi = mid; }
        int end = lo;
        int cnt = end - start;

        if (tid < 192) {
            float4 a = {0.f, 0.f, 0.f, 0.f};
            const float* hb = h + (size_t)b*SS*HH;
            for (int s = start; s < end; ++s) {
                float4 r = *(const float4*)&hb[(size_t)s*HH + tid*4];
                a.x += r.x; a.y += r.y; a.z += r.z; a.w += r.w;
            }
            float inv = (cnt > 0) ? (1.0f / (float)cnt) : 0.0f;
            int p = (blk >> 3) & 1;                 // row bit3 -> swap 8B halves
            pooled32[blk*192 + (tid ^ (p << 1))] = pk4_fp8(a.x*inv, a.y*inv, a.z*inv, a.w*inv);
        }
    } else {
        // ---- W convert+transpose: (768,32000) f32 -> (32000,768) fp8 x64 ----
        int idx = blockIdx.x - NROWS;              // 0..5999
        const int v0 = (idx % (VV/64)) * 64;
        const int k0 = (idx / (VV/64)) * 64;
        #pragma unroll
        for (int j = 0; j < 4; ++j) {
            int ix = tid + j*256;
            int kr = ix >> 4;
            int vs = ix & 15;
            float4 f = *(const float4*)&Wc[(size_t)(k0+kr)*VV + v0 + vs*4];
            S[kr][vs*4+0] = f.x; S[kr][vs*4+1] = f.y;
            S[kr][vs*4+2] = f.z; S[kr][vs*4+3] = f.w;
        }
        __syncthreads();
        #pragma unroll
        for (int j = 0; j < 2; ++j) {
            int ix = tid + j*256;
            int vi = ix >> 3;     // 0..63 (row within tile)
            int ks = ix & 7;      // 0..7 (8B seg)
            float f[8];
            #pragma unroll
            for (int i = 0; i < 8; ++i) f[i] = S[ks*8+i][vi] * WSCALE;
            uint2 o;
            o.x = pk4_fp8(f[0], f[1], f[2], f[3]);
            o.y = pk4_fp8(f[4], f[5], f[6], f[7]);
            int p = (vi >> 3) & 1;                  // row bit3 -> swap 8B halves
            *(uint2*)&Wt[(size_t)(v0+vi)*HH + k0 + (ks ^ p)*8] = o;
        }
    }
}

// ------- fp8 MFMA GEMM: persistent blocks, CONSECUTIVE-run tiles + prefetch -------
// R15 logits core (proven best: 0 conflicts, no spill, 4 blocks/CU, T5) made
// persistent with L2-friendly mapping: block lid owns tiles [lid*8, lid*8+8)
// of its XCD chunk (m-minor order). Next tile = wci+1: same B panel (vt) for
// 7 of 8 transitions -> cross-tile B prefetch is L2-hot (R16's strided mapping
// jumped 4 vt -> FETCH 3x -> regression; this fixes exactly that).
// Per tile: kt=1..10 stage (this,kt+1); kt=11 stages (next,kt0) into buf0
// (WAR-safe post kt=10 barrier); epilogue stages (next,kt1) into buf1 (safe
// post kt=11 barrier) -> prologue stall once per block, epilogue overlapped.
__global__ __launch_bounds__(256, 4) void logits_kernel(
    const unsigned char* __restrict__ Pb, const unsigned char* __restrict__ Wt,
    const float* __restrict__ bc, const int* __restrict__ targets,
    float* __restrict__ pmax, float* __restrict__ psum,
    float* __restrict__ tlogit)
{
    __shared__ unsigned char Alds[2][BM*BK];   // 2 x 8 KB
    __shared__ unsigned char Blds[2][BN*BK];   // 2 x 8 KB

    const int bid = blockIdx.x;     // 0..1023
    const int xcd = bid & 7;
    const int lid = bid >> 3;       // 0..127: position within XCD chunk

    const int tstart = lid * TRUN;
    if (tstart >= NPX) return;      // 3 idle blocks per XCD (1000 = 125*8)
    const int tend = (tstart + TRUN < NPX) ? (tstart + TRUN) : NPX;

    const int t = threadIdx.x;
    const int w = t >> 6;           // wave 0..3
    const int lane = t & 63;
    const int r16 = lane & 15;
    const int kb = lane >> 4;       // 0..3 (8-byte k-seg within 32)
    const int wr = w >> 1;          // 0..1 (M)
    const int wc = w & 1;           // 0..1 (N)

    // staging: one call = 64 lanes x 16 B = 16 rows x 64 B; lane = rr*4 + s
    const int rr = lane >> 2;                     // 0..15 row within call
    const int sg = (lane & 3) ^ ((rr >> 1) & 3);  // pre-swizzled global 16B slot

    #define STAGEP(BUF, R0, V0, KT) do {                                          \
        const int k0_ = (KT) * BK;                                                \
        _Pragma("unroll")                                                         \
        for (int j_ = 0; j_ < 2; ++j_) {                                          \
            int ca_ = w*2 + j_;                                                   \
            GLOAD16(Pb + (size_t)((R0) + ca_*16 + rr)*HH + k0_ + sg*16,           \
                    &Alds[BUF][ca_*1024]);                                        \
            GLOAD16(Wt + (size_t)((V0) + ca_*16 + rr)*HH + k0_ + sg*16,           \
                    &Blds[BUF][ca_*1024]);                                        \
        }                                                                         \
    } while (0)

    const int swz2 = (r16 >> 1) & 3;
    const int swz3 = (r16 >> 3) & 1;

    // prologue: stage first tile's kt0+kt1 (only cold stall in the block)
    {
        const int wg0 = xcd*NPX + tstart;
        const int r0 = (wg0 & (NMT-1)) * BM;
        const int c0 = (wg0 >> 5) * BN;
        STAGEP(0, r0, c0, 0);
        STAGEP(1, r0, c0, 1);
        __syncthreads();
    }

    for (int wci = tstart; wci < tend; ++wci) {
        const int wg = xcd*NPX + wci;
        const int mt = wg & (NMT-1);
        const int vt = wg >> 5;
        const int row0 = mt * BM;
        const int v0 = vt * BN;

        const bool hasNext = (wci + 1 < tend);
        const int wgN = xcd*NPX + (hasNext ? (wci + 1) : tstart);
        const int row0N = (wgN & (NMT-1)) * BM;
        const int v0N = (wgN >> 5) * BN;

        f32x4 acc[4][4];
        #pragma unroll
        for (int mf = 0; mf < 4; ++mf)
            #pragma unroll
            for (int nf = 0; nf < 4; ++nf)
                acc[mf][nf] = (f32x4){0.f, 0.f, 0.f, 0.f};

        #pragma unroll
        for (int kt = 0; kt < NKT; ++kt) {
            const int buf = kt & 1;

            // stage: kt=0 nothing (pre-staged); kt=1..10 -> (this, kt+1);
            // kt=11 -> (next, kt0) into buf0
            if (kt >= 1 && kt + 1 < NKT) {
                STAGEP(buf ^ 1, row0, v0, kt + 1);
            } else if (kt == NKT - 1) {
                if (hasNext) STAGEP(0, row0N, v0N, 0);
            }

            long af[4][2], bfv[4][2];
            #pragma unroll
            for (int ks = 0; ks < 2; ++ks) {
                const int idx8 = ks*4 + kb;                       // 0..7
                const int off = (((idx8 >> 1) ^ swz2) << 4) | (((idx8 & 1) ^ swz3) << 3);
                #pragma unroll
                for (int mf = 0; mf < 4; ++mf)
                    af[mf][ks] = *(const long*)&Alds[buf][(wr*64 + mf*16 + r16)*BK + off];
                #pragma unroll
                for (int nf = 0; nf < 4; ++nf)
                    bfv[nf][ks] = *(const long*)&Blds[buf][(wc*64 + nf*16 + r16)*BK + off];
            }

            __builtin_amdgcn_s_setprio(1);
            #pragma unroll
            for (int ks = 0; ks < 2; ++ks)
                #pragma unroll
                for (int mf = 0; mf < 4; ++mf)
                    #pragma unroll
                    for (int nf = 0; nf < 4; ++nf)
                        acc[mf][nf] = __builtin_amdgcn_mfma_f32_16x16x32_fp8_fp8(
                            af[mf][ks], bfv[nf][ks], acc[mf][nf], 0, 0, 0);
            __builtin_amdgcn_s_setprio(0);

            __syncthreads();
        }

        // stage next tile's kt1 into buf1 (free after kt=11 barrier);
        // its latency hides under the epilogue below
        if (hasNext) STAGEP(1, row0N, v0N, 1);

        // epilogue: unscale + bias + per-row max/sumexp over wave's 64 cols
        const int cchunk = vt*2 + wc;
        float bias[4];
        #pragma unroll
        for (int nf = 0; nf < 4; ++nf) bias[nf] = bc[v0 + wc*64 + nf*16 + r16];

        #pragma unroll
        for (int mf = 0; mf < 4; ++mf) {
            #pragma unroll
            for (int j = 0; j < 4; ++j) {
                const int row = row0 + wr*64 + mf*16 + kb*4 + j;
                float v[4]; float mx = -INFINITY;
                #pragma unroll
                for (int nf = 0; nf < 4; ++nf) {
                    v[nf] = acc[mf][nf][j]*WISCALE + bias[nf];
                    mx = fmaxf(mx, v[nf]);
                }
                #pragma unroll
                for (int off = 1; off < 16; off <<= 1)
                    mx = fmaxf(mx, __shfl_xor(mx, off, 16));
                float se = 0.f;
                #pragma unroll
                for (int nf = 0; nf < 4; ++nf) se += __expf(v[nf] - mx);
                #pragma unroll
                for (int off = 1; off < 16; off <<= 1)
                    se += __shfl_xor(se, off, 16);
                if (r16 == 0) {
                    pmax[(size_t)row*NCHUNK + cchunk] = mx;
                    psum[(size_t)row*NCHUNK + cchunk] = se;
                }
                int tg = targets[row];
                int base = v0 + wc*64 + r16;
                #pragma unroll
                for (int nf = 0; nf < 4; ++nf)
                    if (tg == base + nf*16) tlogit[row] = v[nf];
            }
        }
    }
}

// ---------------- combine chunk partials -> per-row loss ----------------
__global__ __launch_bounds__(256) void reduce_kernel(
    const float* __restrict__ pmax, const float* __restrict__ psum,
    const float* __restrict__ tlogit, const int* __restrict__ targets,
    float* __restrict__ rowloss)
{
    const int row = blockIdx.x;
    const int tid = threadIdx.x;
    float m0 = (tid       < NCHUNK) ? pmax[(size_t)row*NCHUNK + tid]       : -INFINITY;
    float m1 = (tid + 256 < NCHUNK) ? pmax[(size_t)row*NCHUNK + tid + 256] : -INFINITY;
    float mw = fmaxf(m0, m1);
    #pragma unroll
    for (int off = 1; off < 64; off <<= 1)
        mw = fmaxf(mw, __shfl_xor(mw, off));
    __shared__ float smax[4];
    __shared__ float ssum[4];
    const int wave = tid >> 6;
    if ((tid & 63) == 0) smax[wave] = mw;
    __syncthreads();
    float mx = fmaxf(fmaxf(smax[0], smax[1]), fmaxf(smax[2], smax[3]));
    float s = 0.f;
    if (tid       < NCHUNK) s += psum[(size_t)row*NCHUNK + tid]       * __expf(m0 - mx);
    if (tid + 256 < NCHUNK) s += psum[(size_t)row*NCHUNK + tid + 256] * __expf(m1 - mx);
    #pragma unroll
    for (int off = 1; off < 64; off <<= 1)
        s += __shfl_xor(s, off);
    if ((tid & 63) == 0) ssum[wave] = s;
    __syncthreads();
    if (tid == 0) {
        float st = ssum[0] + ssum[1] + ssum[2] + ssum[3];
        float lse = mx + logf(st);
        int tg = targets[row];
        rowloss[row] = (tg != 0) ? (lse - tlogit[row]) : 0.0f;
    }
}

// ---------------- final sum over rows ----------------
__global__ __launch_bounds__(256) void finalize_kernel(
    const float* __restrict__ rowloss, const int* __restrict__ targets,
    float* __restrict__ out)
{
    const int tid = threadIdx.x;
    float s = 0.f; float c = 0.f;
    for (int i = tid; i < NROWS; i += 256) {
        s += rowloss[i];
        c += (targets[i] != 0) ? 1.0f : 0.0f;
    }
    #pragma unroll
    for (int off = 1; off < 64; off <<= 1) {
        s += __shfl_xor(s, off);
        c += __shfl_xor(c, off);
    }
    __shared__ float ss[4], sc[4];
    const int wave = tid >> 6;
    if ((tid & 63) == 0) { ss[wave] = s; sc[wave] = c; }
    __syncthreads();
    if (tid == 0) {
        float st = ss[0]+ss[1]+ss[2]+ss[3];
        float ct = sc[0]+sc[1]+sc[2]+sc[3];
        out[0] = st / fmaxf(ct, 1.0f);
    }
}

extern "C" void kernel_launch(void* const* d_in, const int* in_sizes, int n_in,
                              void* d_out, int out_size, void* d_ws, size_t ws_size,
                              hipStream_t stream) {
    const float* h       = (const float*)d_in[0];   // (16,512,768) f32
    const int*   wid     = (const int*)  d_in[1];   // (16,512) i32
    const int*   targets = (const int*)  d_in[2];   // (16,256) i32
    const float* Wc      = (const float*)d_in[3];   // (768,32000) f32
    const float* bc      = (const float*)d_in[4];   // (32000,) f32
    float* out = (float*)d_out;

    unsigned char* pooled = (unsigned char*)d_ws;                // 4096*768 fp8
    unsigned char* Wt     = pooled + (size_t)NROWS*HH;           // 32000*768 fp8
    float* pmax  = (float*)(Wt + (size_t)HH*VV);                 // 4096*500
    float* psum  = pmax + (size_t)NROWS*NCHUNK;                  // 4096*500
    float* tlog  = psum + (size_t)NROWS*NCHUNK;                  // 4096
    float* rowl  = tlog + NROWS;                                 // 4096

    prep_kernel<<<NROWS + (VV/64)*(HH/64), 256, 0, stream>>>(
        h, wid, (unsigned int*)pooled, Wc, Wt);
    logits_kernel<<<NBLK, 256, 0, stream>>>(
        pooled, Wt, bc, targets, pmax, psum, tlog);
    reduce_kernel<<<NROWS, 256, 0, stream>>>(pmax, psum, tlog, targets, rowl);
    finalize_kernel<<<1, 256, 0, stream>>>(rowl, targets, out);
}

// Round 18
// 221.858 us; speedup vs baseline: 1.2040x; 1.1584x over previous
//
#include <hip/hip_runtime.h>
#include <math.h>

#define BB 16
#define SS 512
#define HH 768
#define WW 256
#define VV 32000
#define NROWS (BB*WW)          // 4096
#define NCHUNK 500             // 64-wide v chunks
#define BM 128
#define BN 128
#define BK 64                  // fp8: 64 bytes per row per k-tile
#define NKT (HH/BK)            // 12
#define NMT (NROWS/BM)         // 32
#define NVT (VV/BN)            // 250
#define NWG (NMT*NVT)          // 8000
#define WSCALE 64.0f
#define WISCALE (1.0f/64.0f)

typedef __attribute__((ext_vector_type(4))) float f32x4;

#define GLOAD16(g, l) __builtin_amdgcn_global_load_lds( \
    (const __attribute__((address_space(1))) void*)(g), \
    (__attribute__((address_space(3))) void*)(l), 16, 0, 0)

// pack 4 floats -> 4 fp8 e4m3 bytes (OCP)
__device__ __forceinline__ unsigned int pk4_fp8(float a0, float a1, float a2, float a3) {
    int r = __builtin_amdgcn_cvt_pk_fp8_f32(a0, a1, 0, false);
    r = __builtin_amdgcn_cvt_pk_fp8_f32(a2, a3, r, true);
    return (unsigned int)r;
}

// ---------------- fused prep: pooling (blocks 0..4095) + W transpose (rest) ----------------
// Both outputs use the half-swap-by-row-bit3 fp8 storage feeding the
// conflict-free LDS read swizzle in logits_kernel.
__global__ __launch_bounds__(256) void prep_kernel(
    const float* __restrict__ h, const int* __restrict__ wid,
    unsigned int* __restrict__ pooled32,
    const float* __restrict__ Wc, unsigned char* __restrict__ Wt)
{
    __shared__ int s_wid[SS];
    __shared__ float S[64][65];
    const int tid = threadIdx.x;

    if (blockIdx.x < NROWS) {
        // ---- pooling: one block per (b, w), binary search over sorted wid ----
        int blk = blockIdx.x;
        int b = blk >> 8;
        int w = blk & 255;
        for (int i = tid; i < SS; i += 256) s_wid[i] = wid[b*SS + i];
        __syncthreads();
        int lo = 0, hi = SS;
        while (lo < hi) { int mid = (lo + hi) >> 1; if (s_wid[mid] < w) lo = mid + 1; else hi = mid; }
        int start = lo;
        hi = SS;
        while (lo < hi) { int mid = (lo + hi) >> 1; if (s_wid[mid] <= w) lo = mid + 1; else hi = mid; }
        int end = lo;
        int cnt = end - start;

        if (tid < 192) {
            float4 a = {0.f, 0.f, 0.f, 0.f};
            const float* hb = h + (size_t)b*SS*HH;
            for (int s = start; s < end; ++s) {
                float4 r = *(const float4*)&hb[(size_t)s*HH + tid*4];
                a.x += r.x; a.y += r.y; a.z += r.z; a.w += r.w;
            }
            float inv = (cnt > 0) ? (1.0f / (float)cnt) : 0.0f;
            int p = (blk >> 3) & 1;                 // row bit3 -> swap 8B halves
            pooled32[blk*192 + (tid ^ (p << 1))] = pk4_fp8(a.x*inv, a.y*inv, a.z*inv, a.w*inv);
        }
    } else {
        // ---- W convert+transpose: (768,32000) f32 -> (32000,768) fp8 x64 ----
        int idx = blockIdx.x - NROWS;              // 0..5999
        const int v0 = (idx % (VV/64)) * 64;
        const int k0 = (idx / (VV/64)) * 64;
        #pragma unroll
        for (int j = 0; j < 4; ++j) {
            int ix = tid + j*256;
            int kr = ix >> 4;
            int vs = ix & 15;
            float4 f = *(const float4*)&Wc[(size_t)(k0+kr)*VV + v0 + vs*4];
            S[kr][vs*4+0] = f.x; S[kr][vs*4+1] = f.y;
            S[kr][vs*4+2] = f.z; S[kr][vs*4+3] = f.w;
        }
        __syncthreads();
        #pragma unroll
        for (int j = 0; j < 2; ++j) {
            int ix = tid + j*256;
            int vi = ix >> 3;     // 0..63 (row within tile)
            int ks = ix & 7;      // 0..7 (8B seg)
            float f[8];
            #pragma unroll
            for (int i = 0; i < 8; ++i) f[i] = S[ks*8+i][vi] * WSCALE;
            uint2 o;
            o.x = pk4_fp8(f[0], f[1], f[2], f[3]);
            o.y = pk4_fp8(f[4], f[5], f[6], f[7]);
            int p = (vi >> 3) & 1;                  // row bit3 -> swap 8B halves
            *(uint2*)&Wt[(size_t)(v0+vi)*HH + k0 + (ks ^ p)*8] = o;
        }
    }
}

// ---------------- fp8 MFMA GEMM, 128x128 tile, BK=64, 4 blocks/CU + T5 ----------------
// The measured-best logits core (R15: ~211us, FETCH 93MB, 0 conflicts, no
// spill). 256 threads = 4 waves (2M x 2N), wave tile 64x64, acc[4][4]=64 VGPR.
// LDS: 2 dbuf x (A 8KB + B 8KB) = 32 KB; launch_bounds(256,4) caps VGPR 128
// -> 4 blocks/CU = 16 waves in 4 INDEPENDENT barrier groups; per-tile grid's
// moving window keeps the concurrent B working set ~4 panels (L2-resident) --
// persistent variants (R16/R17) spread it and regressed.
// m97-style loop: STAGE(kt+1) at top, compiler waits, one barrier per k-step.
// T5 setprio around the MFMA cluster (positive in the independent-block regime).
// Swizzle (conflict-free, measured 0): LDS 16B slot s of row r holds global
// slot s^((r>>1)&3); global storage pre-swaps 8B halves by row bit3; read
// offset covers all 4 r16 bits.
__global__ __launch_bounds__(256, 4) void logits_kernel(
    const unsigned char* __restrict__ Pb, const unsigned char* __restrict__ Wt,
    const float* __restrict__ bc, const int* __restrict__ targets,
    float* __restrict__ pmax, float* __restrict__ psum,
    float* __restrict__ tlogit)
{
    __shared__ unsigned char Alds[2][BM*BK];   // 2 x 8 KB
    __shared__ unsigned char Blds[2][BN*BK];   // 2 x 8 KB

    // XCD swizzle (NWG = 8000, divisible by 8), m-minor within XCD chunk
    const int id = blockIdx.x;
    const int wg = (id & 7) * (NWG/8) + (id >> 3);
    const int mt = wg % NMT;
    const int vt = wg / NMT;

    const int t = threadIdx.x;
    const int w = t >> 6;           // wave 0..3
    const int lane = t & 63;
    const int r16 = lane & 15;
    const int kb = lane >> 4;       // 0..3 (8-byte k-seg within 32)
    const int wr = w >> 1;          // 0..1 (M)
    const int wc = w & 1;           // 0..1 (N)
    const int row0 = mt * BM;
    const int v0 = vt * BN;

    // staging: one call = 64 lanes x 16 B = 16 rows x 64 B; lane = rr*4 + s
    const int rr = lane >> 2;                     // 0..15 row within call
    const int sg = (lane & 3) ^ ((rr >> 1) & 3);  // pre-swizzled global 16B slot

    // A: 8 calls (2/wave), B: 8 calls (2/wave) -> 4 loads/thread per STAGE
    #define STAGE(BUF, KT) do {                                                   \
        const int k0_ = (KT) * BK;                                                \
        _Pragma("unroll")                                                         \
        for (int j_ = 0; j_ < 2; ++j_) {                                          \
            int ca_ = w*2 + j_;                                                   \
            GLOAD16(Pb + (size_t)(row0 + ca_*16 + rr)*HH + k0_ + sg*16,           \
                    &Alds[BUF][ca_*1024]);                                        \
            GLOAD16(Wt + (size_t)(v0 + ca_*16 + rr)*HH + k0_ + sg*16,             \
                    &Blds[BUF][ca_*1024]);                                        \
        }                                                                         \
    } while (0)

    f32x4 acc[4][4];
    #pragma unroll
    for (int mf = 0; mf < 4; ++mf)
        #pragma unroll
        for (int nf = 0; nf < 4; ++nf)
            acc[mf][nf] = (f32x4){0.f, 0.f, 0.f, 0.f};

    STAGE(0, 0);
    __syncthreads();

    const int swz2 = (r16 >> 1) & 3;
    const int swz3 = (r16 >> 3) & 1;

    for (int kt = 0; kt < NKT; ++kt) {
        const int buf = kt & 1;
        if (kt + 1 < NKT) STAGE(buf ^ 1, kt + 1);

        long af[4][2], bfv[4][2];
        #pragma unroll
        for (int ks = 0; ks < 2; ++ks) {
            const int idx8 = ks*4 + kb;                       // 0..7
            const int off = (((idx8 >> 1) ^ swz2) << 4) | (((idx8 & 1) ^ swz3) << 3);
            #pragma unroll
            for (int mf = 0; mf < 4; ++mf)
                af[mf][ks] = *(const long*)&Alds[buf][(wr*64 + mf*16 + r16)*BK + off];
            #pragma unroll
            for (int nf = 0; nf < 4; ++nf)
                bfv[nf][ks] = *(const long*)&Blds[buf][(wc*64 + nf*16 + r16)*BK + off];
        }

        __builtin_amdgcn_s_setprio(1);
        #pragma unroll
        for (int ks = 0; ks < 2; ++ks)
            #pragma unroll
            for (int mf = 0; mf < 4; ++mf)
                #pragma unroll
                for (int nf = 0; nf < 4; ++nf)
                    acc[mf][nf] = __builtin_amdgcn_mfma_f32_16x16x32_fp8_fp8(
                        af[mf][ks], bfv[nf][ks], acc[mf][nf], 0, 0, 0);
        __builtin_amdgcn_s_setprio(0);

        __syncthreads();
    }

    // epilogue: unscale + bias + per-row max/sumexp over this wave's 64 cols
    const int cchunk = vt*2 + wc;
    float bias[4];
    #pragma unroll
    for (int nf = 0; nf < 4; ++nf) bias[nf] = bc[v0 + wc*64 + nf*16 + r16];

    #pragma unroll
    for (int mf = 0; mf < 4; ++mf) {
        #pragma unroll
        for (int j = 0; j < 4; ++j) {
            const int row = row0 + wr*64 + mf*16 + kb*4 + j;
            float v[4]; float mx = -INFINITY;
            #pragma unroll
            for (int nf = 0; nf < 4; ++nf) {
                v[nf] = acc[mf][nf][j]*WISCALE + bias[nf];
                mx = fmaxf(mx, v[nf]);
            }
            #pragma unroll
            for (int off = 1; off < 16; off <<= 1)
                mx = fmaxf(mx, __shfl_xor(mx, off, 16));
            float se = 0.f;
            #pragma unroll
            for (int nf = 0; nf < 4; ++nf) se += __expf(v[nf] - mx);
            #pragma unroll
            for (int off = 1; off < 16; off <<= 1)
                se += __shfl_xor(se, off, 16);
            if (r16 == 0) {
                pmax[(size_t)row*NCHUNK + cchunk] = mx;
                psum[(size_t)row*NCHUNK + cchunk] = se;
            }
            int tg = targets[row];
            int base = v0 + wc*64 + r16;
            #pragma unroll
            for (int nf = 0; nf < 4; ++nf)
                if (tg == base + nf*16) tlogit[row] = v[nf];
        }
    }
}

// ---------------- combine chunk partials -> per-row loss ----------------
__global__ __launch_bounds__(256) void reduce_kernel(
    const float* __restrict__ pmax, const float* __restrict__ psum,
    const float* __restrict__ tlogit, const int* __restrict__ targets,
    float* __restrict__ rowloss)
{
    const int row = blockIdx.x;
    const int tid = threadIdx.x;
    float m0 = (tid       < NCHUNK) ? pmax[(size_t)row*NCHUNK + tid]       : -INFINITY;
    float m1 = (tid + 256 < NCHUNK) ? pmax[(size_t)row*NCHUNK + tid + 256] : -INFINITY;
    float mw = fmaxf(m0, m1);
    #pragma unroll
    for (int off = 1; off < 64; off <<= 1)
        mw = fmaxf(mw, __shfl_xor(mw, off));
    __shared__ float smax[4];
    __shared__ float ssum[4];
    const int wave = tid >> 6;
    if ((tid & 63) == 0) smax[wave] = mw;
    __syncthreads();
    float mx = fmaxf(fmaxf(smax[0], smax[1]), fmaxf(smax[2], smax[3]));
    float s = 0.f;
    if (tid       < NCHUNK) s += psum[(size_t)row*NCHUNK + tid]       * __expf(m0 - mx);
    if (tid + 256 < NCHUNK) s += psum[(size_t)row*NCHUNK + tid + 256] * __expf(m1 - mx);
    #pragma unroll
    for (int off = 1; off < 64; off <<= 1)
        s += __shfl_xor(s, off);
    if ((tid & 63) == 0) ssum[wave] = s;
    __syncthreads();
    if (tid == 0) {
        float st = ssum[0] + ssum[1] + ssum[2] + ssum[3];
        float lse = mx + logf(st);
        int tg = targets[row];
        rowloss[row] = (tg != 0) ? (lse - tlogit[row]) : 0.0f;
    }
}

// ---------------- final sum over rows ----------------
__global__ __launch_bounds__(256) void finalize_kernel(
    const float* __restrict__ rowloss, const int* __restrict__ targets,
    float* __restrict__ out)
{
    const int tid = threadIdx.x;
    float s = 0.f; float c = 0.f;
    for (int i = tid; i < NROWS; i += 256) {
        s += rowloss[i];
        c += (targets[i] != 0) ? 1.0f : 0.0f;
    }
    #pragma unroll
    for (int off = 1; off < 64; off <<= 1) {
        s += __shfl_xor(s, off);
        c += __shfl_xor(c, off);
    }
    __shared__ float ss[4], sc[4];
    const int wave = tid >> 6;
    if ((tid & 63) == 0) { ss[wave] = s; sc[wave] = c; }
    __syncthreads();
    if (tid == 0) {
        float st = ss[0]+ss[1]+ss[2]+ss[3];
        float ct = sc[0]+sc[1]+sc[2]+sc[3];
        out[0] = st / fmaxf(ct, 1.0f);
    }
}

extern "C" void kernel_launch(void* const* d_in, const int* in_sizes, int n_in,
                              void* d_out, int out_size, void* d_ws, size_t ws_size,
                              hipStream_t stream) {
    const float* h       = (const float*)d_in[0];   // (16,512,768) f32
    const int*   wid     = (const int*)  d_in[1];   // (16,512) i32
    const int*   targets = (const int*)  d_in[2];   // (16,256) i32
    const float* Wc      = (const float*)d_in[3];   // (768,32000) f32
    const float* bc      = (const float*)d_in[4];   // (32000,) f32
    float* out = (float*)d_out;

    unsigned char* pooled = (unsigned char*)d_ws;                // 4096*768 fp8
    unsigned char* Wt     = pooled + (size_t)NROWS*HH;           // 32000*768 fp8
    float* pmax  = (float*)(Wt + (size_t)HH*VV);                 // 4096*500
    float* psum  = pmax + (size_t)NROWS*NCHUNK;                  // 4096*500
    float* tlog  = psum + (size_t)NROWS*NCHUNK;                  // 4096
    float* rowl  = tlog + NROWS;                                 // 4096

    prep_kernel<<<NROWS + (VV/64)*(HH/64), 256, 0, stream>>>(
        h, wid, (unsigned int*)pooled, Wc, Wt);
    logits_kernel<<<NWG, 256, 0, stream>>>(
        pooled, Wt, bc, targets, pmax, psum, tlog);
    reduce_kernel<<<NROWS, 256, 0, stream>>>(pmax, psum, tlog, targets, rowl);
    finalize_kernel<<<1, 256, 0, stream>>>(rowl, targets, out);
}